// Round 3
// baseline (234.266 us; speedup 1.0000x reference)
//
#include <hip/hip_runtime.h>
#include <hip/hip_bf16.h>
#include <stdint.h>

#define N_TOK 16384
#define HDIM  1024
#define NE    8

#define BM 256
#define BN 256
#define BK 64
#define NKT (HDIM / BK)       // 16 K-tiles
#define MT_MAX (N_TOK / BM)   // 64
#define NT_N (HDIM / BN)      // 4
#define GRID_GEMM (NE * MT_MAX * NT_N)  // 2048, %8 == 0

typedef __attribute__((ext_vector_type(8))) short          bf16x8;
typedef __attribute__((ext_vector_type(8))) unsigned short ushort8;
typedef __attribute__((ext_vector_type(4))) unsigned short ushort4v;
typedef __attribute__((ext_vector_type(4))) float          f32x4;

__device__ __forceinline__ unsigned short f2bf(float f) {
  union { float f; uint32_t u; } c; c.f = f;
  uint32_t u = c.u;
  uint32_t r = (u + 0x7fffu + ((u >> 16) & 1u)) >> 16;
  return (unsigned short)r;
}

__device__ __forceinline__ void gload_lds16(const void* g, void* l) {
  __builtin_amdgcn_global_load_lds((const __attribute__((address_space(1))) void*)g,
                                   (__attribute__((address_space(3))) void*)l, 16, 0, 0);
}

// expert prefix: returns base offset and count for expert e from counts[0..7]
__device__ __forceinline__ void expert_range(const int* __restrict__ counts, int e,
                                             int& base, int& cnt) {
  int run = 0; base = 0; cnt = 0;
#pragma unroll
  for (int i = 0; i < NE; ++i) {
    int c = counts[i];
    if (i == e) { base = run; cnt = c; }
    run += c;
  }
}

// ---------------------------------------------------------------------------
// Gate: logits = tokens @ gate_w^T (f64 accum), top-1 argmax -> eid.
// Fuses token f32->bf16 conversion. One wave per token.
// ---------------------------------------------------------------------------
__global__ __launch_bounds__(256) void gate_kernel(
    const float* __restrict__ tokens, const float* __restrict__ gate_w,
    unsigned short* __restrict__ tokB, int* __restrict__ eid)
{
  int wid  = threadIdx.x >> 6;
  int lane = threadIdx.x & 63;
  int n    = blockIdx.x * 4 + wid;

  const float* trow = tokens + (size_t)n * HDIM;
  float4 x[4];
#pragma unroll
  for (int i = 0; i < 4; ++i)
    x[i] = *(const float4*)(trow + i * 256 + lane * 4);

  unsigned short* drow = tokB + (size_t)n * HDIM;
#pragma unroll
  for (int i = 0; i < 4; ++i) {
    ushort4v o;
    o[0] = f2bf(x[i].x); o[1] = f2bf(x[i].y);
    o[2] = f2bf(x[i].z); o[3] = f2bf(x[i].w);
    *(ushort4v*)(drow + i * 256 + lane * 4) = o;
  }

  double acc[NE];
#pragma unroll
  for (int e = 0; e < NE; ++e) {
    const float* grow = gate_w + e * HDIM;
    double a = 0.0;
#pragma unroll
    for (int i = 0; i < 4; ++i) {
      float4 g = *(const float4*)(grow + i * 256 + lane * 4);
      a += (double)x[i].x * g.x + (double)x[i].y * g.y
         + (double)x[i].z * g.z + (double)x[i].w * g.w;
    }
    acc[e] = a;
  }
#pragma unroll
  for (int off = 32; off; off >>= 1) {
#pragma unroll
    for (int e = 0; e < NE; ++e) acc[e] += __shfl_xor(acc[e], off);
  }
  if (lane == 0) {
    int best = 0; double bv = acc[0];
#pragma unroll
    for (int e = 1; e < NE; ++e) if (acc[e] > bv) { bv = acc[e]; best = e; }
    eid[n] = best;
  }
}

// ---------------------------------------------------------------------------
// Rank: LDS histogram per 256-token block; 8 global atomics per block.
// ---------------------------------------------------------------------------
__global__ __launch_bounds__(256) void rank_kernel(
    const int* __restrict__ eid, int* __restrict__ rank, int* __restrict__ counts)
{
  __shared__ int h[NE];
  __shared__ int bbase[NE];
  int t = threadIdx.x;
  int n = blockIdx.x * 256 + t;
  if (t < NE) h[t] = 0;
  __syncthreads();
  int e = eid[n];
  int r = atomicAdd(&h[e], 1);
  __syncthreads();
  if (t < NE) bbase[t] = atomicAdd(&counts[t], h[t]);
  __syncthreads();
  rank[n] = bbase[e] + r;
}

// perm: computes expert offsets inline (prefix over counts), scatters topos.
__global__ __launch_bounds__(256) void perm_kernel(
    const int* __restrict__ counts, const int* __restrict__ eid,
    const int* __restrict__ rank, int* __restrict__ topos)
{
  __shared__ int off[NE];
  int t = threadIdx.x;
  if (t == 0) {
    int run = 0;
#pragma unroll
    for (int e = 0; e < NE; ++e) { off[e] = run; run += counts[e]; }
  }
  __syncthreads();
  int n = blockIdx.x * 256 + t;
  topos[off[eid[n]] + rank[n]] = n;
}

// f32 -> bf16 for both weight tensors in one launch. 8 elems/thread.
// blocks 0..4095 -> w1 (8.39M elems), 4096..8191 -> w2.
__global__ __launch_bounds__(256) void cvt2_kernel(
    const float* __restrict__ w1, const float* __restrict__ w2,
    unsigned short* __restrict__ w1B, unsigned short* __restrict__ w2B)
{
  int b = blockIdx.x;
  const float* src; unsigned short* dst; size_t i;
  if (b < 4096) { src = w1; dst = w1B; i = (size_t)b * 256 + threadIdx.x; }
  else          { src = w2; dst = w2B; i = (size_t)(b - 4096) * 256 + threadIdx.x; }
  const float4* s = (const float4*)src + i * 2;
  float4 a = s[0], c = s[1];
  ushort8 o;
  o[0] = f2bf(a.x); o[1] = f2bf(a.y); o[2] = f2bf(a.z); o[3] = f2bf(a.w);
  o[4] = f2bf(c.x); o[5] = f2bf(c.y); o[6] = f2bf(c.z); o[7] = f2bf(c.w);
  ((ushort8*)dst)[i] = o;
}

// ---------------------------------------------------------------------------
// Grouped GEMM, 256x256 tile, BK=64, 8 waves (2Mx4N), double-buffered LDS,
// one raw s_barrier per K-tile with counted prefetch (stage(t+1) hides under
// MFMA(t)).  XCD-chunked swizzle: expert e's blocks -> XCD e.
// ---------------------------------------------------------------------------
#define GEMM_PREAMBLE(APTR_EXPR)                                               \
  int bid = blockIdx.x;                                                        \
  int logical = (bid & 7) * (GRID_GEMM / 8) + (bid >> 3);                      \
  int e   = logical >> 8;                                                      \
  int rem = logical & 255;                                                     \
  int mt  = rem >> 2, nt = rem & 3;                                            \
  int base, cnt;                                                               \
  expert_range(counts, e, base, cnt);                                          \
  if (mt * BM >= cnt) return;                                                  \
  __shared__ unsigned short Alds[2][BM * BK];                                  \
  __shared__ unsigned short Blds[2][BN * BK];                                  \
  int t    = threadIdx.x;                                                      \
  int kc   = t & 7;      /* 16B chunk within 64-elem row */                    \
  int row0 = t >> 3;     /* 0..63 */                                           \
  int lane = t & 63, wid = t >> 6;                                             \
  int wr = wid >> 2, wc = wid & 3;                                             \
  f32x4 acc[8][4] = {};                                                        \
  int arow0 = wr * 128 + (lane & 15);                                          \
  int brow0 = wc * 64  + (lane & 15);                                          \
  int acol  = (lane >> 4) * 8;

#define GEMM_STAGE(buf, kt)                                                    \
  _Pragma("unroll")                                                            \
  for (int r = 0; r < 4; ++r) {                                                \
    gload_lds16(APTR(r, kt), &Alds[buf][t * 8 + 4096 * r]);                    \
    gload_lds16(bsrc + (size_t)(kt) * BK + (size_t)(64 * r) * HDIM,            \
                &Blds[buf][t * 8 + 4096 * r]);                                 \
  }

#define GEMM_COMPUTE(buf)                                                      \
  _Pragma("unroll")                                                            \
  for (int ks = 0; ks < 2; ++ks) {                                             \
    bf16x8 af[8], bv[4];                                                       \
    _Pragma("unroll")                                                          \
    for (int m = 0; m < 8; ++m)                                                \
      af[m] = *(const bf16x8*)(&Alds[buf][(arow0 + m * 16) * BK + ks * 32 + acol]); \
    _Pragma("unroll")                                                          \
    for (int n2 = 0; n2 < 4; ++n2)                                             \
      bv[n2] = *(const bf16x8*)(&Blds[buf][(brow0 + n2 * 16) * BK + ks * 32 + acol]); \
    asm volatile("s_waitcnt lgkmcnt(0)" ::: "memory");                         \
    __builtin_amdgcn_sched_barrier(0);                                         \
    _Pragma("unroll")                                                          \
    for (int m = 0; m < 8; ++m)                                                \
      _Pragma("unroll")                                                        \
      for (int n2 = 0; n2 < 4; ++n2)                                           \
        acc[m][n2] = __builtin_amdgcn_mfma_f32_16x16x32_bf16(                  \
            af[m], bv[n2], acc[m][n2], 0, 0, 0);                               \
  }

#define GEMM_MAINLOOP()                                                        \
  GEMM_STAGE(0, 0);                                                            \
  asm volatile("s_waitcnt vmcnt(0)" ::: "memory");                             \
  __builtin_amdgcn_s_barrier();                                                \
  __builtin_amdgcn_sched_barrier(0);                                           \
  int cur = 0;                                                                 \
  for (int kt = 0; kt < NKT - 1; ++kt) {                                       \
    GEMM_STAGE(cur ^ 1, kt + 1);                                               \
    GEMM_COMPUTE(cur);                                                         \
    asm volatile("s_waitcnt vmcnt(0)" ::: "memory");                           \
    __builtin_amdgcn_s_barrier();                                              \
    __builtin_amdgcn_sched_barrier(0);                                         \
    cur ^= 1;                                                                  \
  }                                                                            \
  GEMM_COMPUTE(cur);

__global__ __launch_bounds__(512, 2) void gemm1_kernel(
    const unsigned short* __restrict__ tokB,  // [N][H] token order
    const unsigned short* __restrict__ w1B,   // [E][H][H]
    const float* __restrict__ b1,             // [E][H]
    const int* __restrict__ counts,
    const int* __restrict__ topos,
    unsigned short* __restrict__ Hbuf)        // [N][H] compacted
{
  GEMM_PREAMBLE()
  // gathered A rows
  int tokr[4];
#pragma unroll
  for (int r = 0; r < 4; ++r) {
    int pos = base + mt * BM + row0 + 64 * r;
    if (pos > N_TOK - 1) pos = N_TOK - 1;
    tokr[r] = topos[pos];
  }
  const unsigned short* bsrc =
      w1B + ((size_t)e << 20) + (size_t)(nt * BN + row0) * HDIM + kc * 8;
#define APTR(r, kt) (tokB + (size_t)tokr[r] * HDIM + (kt) * BK + kc * 8)
  GEMM_MAINLOOP()
#undef APTR

  int crow0 = wr * 128 + (lane >> 4) * 4;
  int ccol0 = wc * 64  + (lane & 15);
  float bias[4];
#pragma unroll
  for (int n2 = 0; n2 < 4; ++n2)
    bias[n2] = b1[e * HDIM + nt * BN + ccol0 + n2 * 16];
#pragma unroll
  for (int m = 0; m < 8; ++m) {
#pragma unroll
    for (int j = 0; j < 4; ++j) {
      int row = crow0 + m * 16 + j;
      if (mt * BM + row < cnt) {
        size_t orow = (size_t)(base + mt * BM + row) * HDIM + nt * BN;
#pragma unroll
        for (int n2 = 0; n2 < 4; ++n2) {
          float v = acc[m][n2][j] + bias[n2];
          v = v > 0.f ? v : 0.f;
          Hbuf[orow + ccol0 + n2 * 16] = f2bf(v);
        }
      }
    }
  }
}

__global__ __launch_bounds__(512, 2) void gemm2_kernel(
    const unsigned short* __restrict__ Hbuf,  // [N][H] compacted
    const unsigned short* __restrict__ w2B,   // [E][H][H]
    const float* __restrict__ b2,             // [E][H]
    const int* __restrict__ counts,
    const int* __restrict__ topos,
    float* __restrict__ out)                  // [N][H] token order
{
  GEMM_PREAMBLE()
  int arows[4];
#pragma unroll
  for (int r = 0; r < 4; ++r) {
    int pos = base + mt * BM + row0 + 64 * r;
    arows[r] = pos > N_TOK - 1 ? N_TOK - 1 : pos;
  }
  const unsigned short* bsrc =
      w2B + ((size_t)e << 20) + (size_t)(nt * BN + row0) * HDIM + kc * 8;
#define APTR(r, kt) (Hbuf + (size_t)arows[r] * HDIM + (kt) * BK + kc * 8)
  GEMM_MAINLOOP()
#undef APTR

  int crow0 = wr * 128 + (lane >> 4) * 4;
  int ccol0 = wc * 64  + (lane & 15);
  float bias[4];
#pragma unroll
  for (int n2 = 0; n2 < 4; ++n2)
    bias[n2] = b2[e * HDIM + nt * BN + ccol0 + n2 * 16];
#pragma unroll
  for (int m = 0; m < 8; ++m) {
#pragma unroll
    for (int j = 0; j < 4; ++j) {
      int row = crow0 + m * 16 + j;
      if (mt * BM + row < cnt) {
        int tok = topos[base + mt * BM + row];
        size_t orow = (size_t)tok * HDIM + nt * BN;
#pragma unroll
        for (int n2 = 0; n2 < 4; ++n2)
          out[orow + ccol0 + n2 * 16] = acc[m][n2][j] + bias[n2];
      }
    }
  }
}

extern "C" void kernel_launch(void* const* d_in, const int* in_sizes, int n_in,
                              void* d_out, int out_size, void* d_ws, size_t ws_size,
                              hipStream_t stream) {
  (void)in_sizes; (void)n_in; (void)out_size; (void)ws_size;
  const float* tokens = (const float*)d_in[0];
  const float* gate_w = (const float*)d_in[1];
  const float* w1     = (const float*)d_in[2];
  const float* b1     = (const float*)d_in[3];
  const float* w2     = (const float*)d_in[4];
  const float* b2     = (const float*)d_in[5];
  float* out          = (float*)d_out;

  char* ws = (char*)d_ws;
  size_t o = 0;
  int* counts = (int*)(ws + o); o += 256;
  int* eid    = (int*)(ws + o); o += (size_t)N_TOK * 4;
  int* rank   = (int*)(ws + o); o += (size_t)N_TOK * 4;
  int* topos  = (int*)(ws + o); o += (size_t)N_TOK * 4;
  unsigned short* tokB = (unsigned short*)(ws + o); o += (size_t)N_TOK * HDIM * 2;
  unsigned short* w1B  = (unsigned short*)(ws + o); o += (size_t)NE * HDIM * HDIM * 2;
  unsigned short* w2B  = (unsigned short*)(ws + o); o += (size_t)NE * HDIM * HDIM * 2;
  unsigned short* Hbuf = (unsigned short*)(ws + o); o += (size_t)N_TOK * HDIM * 2;

  hipMemsetAsync(counts, 0, 64, stream);
  gate_kernel<<<N_TOK / 4, 256, 0, stream>>>(tokens, gate_w, tokB, eid);
  cvt2_kernel<<<8192, 256, 0, stream>>>(w1, w2, w1B, w2B);
  rank_kernel<<<N_TOK / 256, 256, 0, stream>>>(eid, rank, counts);
  perm_kernel<<<N_TOK / 256, 256, 0, stream>>>(counts, eid, rank, topos);
  gemm1_kernel<<<GRID_GEMM, 512, 0, stream>>>(tokB, w1B, b1, counts, topos, Hbuf);
  gemm2_kernel<<<GRID_GEMM, 512, 0, stream>>>(Hbuf, w2B, b2, counts, topos, out);
}

// Round 4
// 192.041 us; speedup vs baseline: 1.2199x; 1.2199x over previous
//
#include <hip/hip_runtime.h>
#include <hip/hip_bf16.h>
#include <stdint.h>

#define N_TOK 16384
#define HDIM  1024
#define NE    8

#define BM 128
#define BN 128
#define BK 64
#define NKT (HDIM / BK)            // 16
#define NT_N (HDIM / BN)           // 8
#define MAXTILES (N_TOK / BM + NE) // 136 worst-case row-tiles
#define GRID_GEMM (MAXTILES * NT_N)

typedef __attribute__((ext_vector_type(8))) short          bf16x8;
typedef __attribute__((ext_vector_type(8))) unsigned short ushort8;
typedef __attribute__((ext_vector_type(4))) unsigned short ushort4v;
typedef __attribute__((ext_vector_type(4))) float          f32x4;

__device__ __forceinline__ unsigned short f2bf(float f) {
  union { float f; uint32_t u; } c; c.f = f;
  uint32_t u = c.u;
  uint32_t r = (u + 0x7fffu + ((u >> 16) & 1u)) >> 16;
  return (unsigned short)r;
}

__device__ __forceinline__ void gload_lds16(const void* g, void* l) {
  __builtin_amdgcn_global_load_lds((const __attribute__((address_space(1))) void*)g,
                                   (__attribute__((address_space(3))) void*)l, 16, 0, 0);
}

__device__ __forceinline__ void expert_range(const int* __restrict__ counts, int e,
                                             int& base, int& cnt) {
  int run = 0; base = 0; cnt = 0;
#pragma unroll
  for (int i = 0; i < NE; ++i) {
    int c = counts[i];
    if (i == e) { base = run; cnt = c; }
    run += c;
  }
}

// ---------------------------------------------------------------------------
// Gate: logits = tokens @ gate_w^T (f64 accum), top-1 argmax -> eid.
// Fuses token f32->bf16 conversion. One wave per token.
// ---------------------------------------------------------------------------
__global__ __launch_bounds__(256) void gate_kernel(
    const float* __restrict__ tokens, const float* __restrict__ gate_w,
    unsigned short* __restrict__ tokB, int* __restrict__ eid)
{
  int wid  = threadIdx.x >> 6;
  int lane = threadIdx.x & 63;
  int n    = blockIdx.x * 4 + wid;

  const float* trow = tokens + (size_t)n * HDIM;
  float4 x[4];
#pragma unroll
  for (int i = 0; i < 4; ++i)
    x[i] = *(const float4*)(trow + i * 256 + lane * 4);

  unsigned short* drow = tokB + (size_t)n * HDIM;
#pragma unroll
  for (int i = 0; i < 4; ++i) {
    ushort4v o;
    o[0] = f2bf(x[i].x); o[1] = f2bf(x[i].y);
    o[2] = f2bf(x[i].z); o[3] = f2bf(x[i].w);
    *(ushort4v*)(drow + i * 256 + lane * 4) = o;
  }

  double acc[NE];
#pragma unroll
  for (int e = 0; e < NE; ++e) {
    const float* grow = gate_w + e * HDIM;
    double a = 0.0;
#pragma unroll
    for (int i = 0; i < 4; ++i) {
      float4 g = *(const float4*)(grow + i * 256 + lane * 4);
      a += (double)x[i].x * g.x + (double)x[i].y * g.y
         + (double)x[i].z * g.z + (double)x[i].w * g.w;
    }
    acc[e] = a;
  }
#pragma unroll
  for (int off = 32; off; off >>= 1) {
#pragma unroll
    for (int e = 0; e < NE; ++e) acc[e] += __shfl_xor(acc[e], off);
  }
  if (lane == 0) {
    int best = 0; double bv = acc[0];
#pragma unroll
    for (int e = 1; e < NE; ++e) if (acc[e] > bv) { bv = acc[e]; best = e; }
    eid[n] = best;
  }
}

// ---------------------------------------------------------------------------
// Rank: LDS histogram per 256-token block; 8 global atomics per block.
// ---------------------------------------------------------------------------
__global__ __launch_bounds__(256) void rank_kernel(
    const int* __restrict__ eid, int* __restrict__ rank, int* __restrict__ counts)
{
  __shared__ int h[NE];
  __shared__ int bbase[NE];
  int t = threadIdx.x;
  int n = blockIdx.x * 256 + t;
  if (t < NE) h[t] = 0;
  __syncthreads();
  int e = eid[n];
  int r = atomicAdd(&h[e], 1);
  __syncthreads();
  if (t < NE) bbase[t] = atomicAdd(&counts[t], h[t]);
  __syncthreads();
  rank[n] = bbase[e] + r;
}

// perm: prefix over counts inline, scatter token index into expert-sorted order
__global__ __launch_bounds__(256) void perm_kernel(
    const int* __restrict__ counts, const int* __restrict__ eid,
    const int* __restrict__ rank, int* __restrict__ topos)
{
  __shared__ int off[NE];
  int t = threadIdx.x;
  if (t == 0) {
    int run = 0;
#pragma unroll
    for (int e = 0; e < NE; ++e) { off[e] = run; run += counts[e]; }
  }
  __syncthreads();
  int n = blockIdx.x * 256 + t;
  topos[off[eid[n]] + rank[n]] = n;
}

// tilemap: enumerate active (e, mt) row-tiles -> compact grid for the GEMMs.
// tmeta[0] = n_tiles; tmeta[1+i] = (mt<<3)|e
__global__ void tilemap_kernel(const int* __restrict__ counts, int* __restrict__ tmeta) {
  if (threadIdx.x == 0) {
    int idx = 0;
    for (int e = 0; e < NE; ++e) {
      int ntile = (counts[e] + BM - 1) / BM;
      for (int mt = 0; mt < ntile; ++mt) tmeta[1 + idx++] = (mt << 3) | e;
    }
    tmeta[0] = idx;
  }
}

// f32 -> bf16 for both weight tensors in one launch. 8 elems/thread.
__global__ __launch_bounds__(256) void cvt2_kernel(
    const float* __restrict__ w1, const float* __restrict__ w2,
    unsigned short* __restrict__ w1B, unsigned short* __restrict__ w2B)
{
  int b = blockIdx.x;
  const float* src; unsigned short* dst; size_t i;
  if (b < 4096) { src = w1; dst = w1B; i = (size_t)b * 256 + threadIdx.x; }
  else          { src = w2; dst = w2B; i = (size_t)(b - 4096) * 256 + threadIdx.x; }
  const float4* s = (const float4*)src + i * 2;
  float4 a = s[0], c = s[1];
  ushort8 o;
  o[0] = f2bf(a.x); o[1] = f2bf(a.y); o[2] = f2bf(a.z); o[3] = f2bf(a.w);
  o[4] = f2bf(c.x); o[5] = f2bf(c.y); o[6] = f2bf(c.z); o[7] = f2bf(c.w);
  ((ushort8*)dst)[i] = o;
}

// ---------------------------------------------------------------------------
// Grouped GEMM, m97 structure: 128x128 tile, BK=64, 4 waves (2x2), single
// LDS buffer, 2 syncthreads per K-tile, compiler-scheduled waits.
// LDS chunk-XOR swizzle (chunk ^= row&7) applied on the per-lane GLOBAL
// source address (global_load_lds dest stays linear) and on the ds_read side.
// Compact grid via tilemap -> ~4 co-resident blocks/CU hide the stage drain.
// ---------------------------------------------------------------------------
#define GEMM_PREAMBLE()                                                        \
  int tile = blockIdx.x >> 3;                                                  \
  int nt   = blockIdx.x & 7;                                                   \
  if (tile >= tmeta[0]) return;                                                \
  int ent = tmeta[1 + tile];                                                   \
  int e = ent & 7, mt = ent >> 3;                                              \
  int base, cnt;                                                               \
  expert_range(counts, e, base, cnt);                                          \
  __shared__ unsigned short Alds[BM * BK];                                     \
  __shared__ unsigned short Blds[BN * BK];                                     \
  int t    = threadIdx.x;                                                      \
  int kc   = t & 7;            /* 16B chunk within row */                      \
  int rowi = t >> 3;           /* 0..31 */                                     \
  int sch  = kc ^ (rowi & 7);  /* inverse-swizzled source chunk */             \
  int lane = t & 63, wid = t >> 6;                                             \
  int wr = wid >> 1, wc = wid & 1;                                             \
  f32x4 acc[4][4] = {};                                                        \
  int arow0 = wr * 64 + (lane & 15);                                           \
  int brow0 = wc * 64 + (lane & 15);                                           \
  int hi    = lane >> 4;       /* 0..3 */                                      \
  int xo    = lane & 7;        /* read-side XOR */

#define GEMM_STAGE(kt)                                                         \
  _Pragma("unroll")                                                            \
  for (int r = 0; r < 4; ++r) {                                                \
    gload_lds16(APTR(r, kt), Alds + t * 8 + 2048 * r);                         \
    gload_lds16(bsrc + (size_t)(kt) * BK + (size_t)(32 * r) * HDIM,            \
                Blds + t * 8 + 2048 * r);                                      \
  }

#define GEMM_COMPUTE()                                                         \
  _Pragma("unroll")                                                            \
  for (int ks = 0; ks < 2; ++ks) {                                             \
    int ch = ((ks * 4 + hi) ^ xo) * 8;                                         \
    bf16x8 af[4], bv[4];                                                       \
    _Pragma("unroll")                                                          \
    for (int m = 0; m < 4; ++m)                                                \
      af[m] = *(const bf16x8*)(Alds + (arow0 + m * 16) * BK + ch);             \
    _Pragma("unroll")                                                          \
    for (int n2 = 0; n2 < 4; ++n2)                                             \
      bv[n2] = *(const bf16x8*)(Blds + (brow0 + n2 * 16) * BK + ch);           \
    _Pragma("unroll")                                                          \
    for (int m = 0; m < 4; ++m)                                                \
      _Pragma("unroll")                                                        \
      for (int n2 = 0; n2 < 4; ++n2)                                           \
        acc[m][n2] = __builtin_amdgcn_mfma_f32_16x16x32_bf16(                  \
            af[m], bv[n2], acc[m][n2], 0, 0, 0);                               \
  }

#define GEMM_MAINLOOP()                                                        \
  for (int kt = 0; kt < NKT; ++kt) {                                           \
    __syncthreads();                                                           \
    GEMM_STAGE(kt);                                                            \
    __syncthreads();                                                           \
    GEMM_COMPUTE();                                                            \
  }

__global__ __launch_bounds__(256) void gemm1_kernel(
    const unsigned short* __restrict__ tokB,  // [N][H] token order
    const unsigned short* __restrict__ w1B,   // [E][H][H]
    const float* __restrict__ b1,             // [E][H]
    const int* __restrict__ counts,
    const int* __restrict__ tmeta,
    const int* __restrict__ topos,
    unsigned short* __restrict__ Hbuf)        // [N][H] compacted
{
  GEMM_PREAMBLE()
  int tokr[4];
#pragma unroll
  for (int r = 0; r < 4; ++r) {
    int pos = base + mt * BM + rowi + 32 * r;
    if (pos > N_TOK - 1) pos = N_TOK - 1;
    tokr[r] = topos[pos];
  }
  const unsigned short* bsrc =
      w1B + ((size_t)e << 20) + (size_t)(nt * BN + rowi) * HDIM + sch * 8;
#define APTR(r, kt) (tokB + (size_t)tokr[r] * HDIM + (kt) * BK + sch * 8)
  GEMM_MAINLOOP()
#undef APTR

  int crow0 = wr * 64 + (lane >> 4) * 4;
  int ccol0 = wc * 64 + (lane & 15);
  float bias[4];
#pragma unroll
  for (int n2 = 0; n2 < 4; ++n2)
    bias[n2] = b1[e * HDIM + nt * BN + ccol0 + n2 * 16];
#pragma unroll
  for (int m = 0; m < 4; ++m) {
#pragma unroll
    for (int j = 0; j < 4; ++j) {
      int row = crow0 + m * 16 + j;
      if (mt * BM + row < cnt) {
        size_t orow = (size_t)(base + mt * BM + row) * HDIM + nt * BN;
#pragma unroll
        for (int n2 = 0; n2 < 4; ++n2) {
          float v = acc[m][n2][j] + bias[n2];
          v = v > 0.f ? v : 0.f;
          Hbuf[orow + ccol0 + n2 * 16] = f2bf(v);
        }
      }
    }
  }
}

__global__ __launch_bounds__(256) void gemm2_kernel(
    const unsigned short* __restrict__ Hbuf,  // [N][H] compacted
    const unsigned short* __restrict__ w2B,   // [E][H][H]
    const float* __restrict__ b2,             // [E][H]
    const int* __restrict__ counts,
    const int* __restrict__ tmeta,
    const int* __restrict__ topos,
    float* __restrict__ out)                  // [N][H] token order
{
  GEMM_PREAMBLE()
  int arows[4];
#pragma unroll
  for (int r = 0; r < 4; ++r) {
    int pos = base + mt * BM + rowi + 32 * r;
    arows[r] = pos > N_TOK - 1 ? N_TOK - 1 : pos;
  }
  const unsigned short* bsrc =
      w2B + ((size_t)e << 20) + (size_t)(nt * BN + rowi) * HDIM + sch * 8;
#define APTR(r, kt) (Hbuf + (size_t)arows[r] * HDIM + (kt) * BK + sch * 8)
  GEMM_MAINLOOP()
#undef APTR

  int crow0 = wr * 64 + (lane >> 4) * 4;
  int ccol0 = wc * 64 + (lane & 15);
  float bias[4];
#pragma unroll
  for (int n2 = 0; n2 < 4; ++n2)
    bias[n2] = b2[e * HDIM + nt * BN + ccol0 + n2 * 16];
#pragma unroll
  for (int m = 0; m < 4; ++m) {
#pragma unroll
    for (int j = 0; j < 4; ++j) {
      int row = crow0 + m * 16 + j;
      if (mt * BM + row < cnt) {
        int tok = topos[base + mt * BM + row];
        size_t orow = (size_t)tok * HDIM + nt * BN;
#pragma unroll
        for (int n2 = 0; n2 < 4; ++n2)
          out[orow + ccol0 + n2 * 16] = acc[m][n2][j] + bias[n2];
      }
    }
  }
}

extern "C" void kernel_launch(void* const* d_in, const int* in_sizes, int n_in,
                              void* d_out, int out_size, void* d_ws, size_t ws_size,
                              hipStream_t stream) {
  (void)in_sizes; (void)n_in; (void)out_size; (void)ws_size;
  const float* tokens = (const float*)d_in[0];
  const float* gate_w = (const float*)d_in[1];
  const float* w1     = (const float*)d_in[2];
  const float* b1     = (const float*)d_in[3];
  const float* w2     = (const float*)d_in[4];
  const float* b2     = (const float*)d_in[5];
  float* out          = (float*)d_out;

  char* ws = (char*)d_ws;
  size_t o = 0;
  int* counts = (int*)(ws + o); o += 256;
  int* tmeta  = (int*)(ws + o); o += 1024;                 // n_tiles + entries
  int* eid    = (int*)(ws + o); o += (size_t)N_TOK * 4;
  int* rank   = (int*)(ws + o); o += (size_t)N_TOK * 4;
  int* topos  = (int*)(ws + o); o += (size_t)N_TOK * 4;
  unsigned short* tokB = (unsigned short*)(ws + o); o += (size_t)N_TOK * HDIM * 2;
  unsigned short* w1B  = (unsigned short*)(ws + o); o += (size_t)NE * HDIM * HDIM * 2;
  unsigned short* w2B  = (unsigned short*)(ws + o); o += (size_t)NE * HDIM * HDIM * 2;
  unsigned short* Hbuf = (unsigned short*)(ws + o); o += (size_t)N_TOK * HDIM * 2;

  hipMemsetAsync(counts, 0, 64, stream);
  gate_kernel<<<N_TOK / 4, 256, 0, stream>>>(tokens, gate_w, tokB, eid);
  cvt2_kernel<<<8192, 256, 0, stream>>>(w1, w2, w1B, w2B);
  rank_kernel<<<N_TOK / 256, 256, 0, stream>>>(eid, rank, counts);
  perm_kernel<<<N_TOK / 256, 256, 0, stream>>>(counts, eid, rank, topos);
  tilemap_kernel<<<1, 64, 0, stream>>>(counts, tmeta);
  gemm1_kernel<<<GRID_GEMM, 256, 0, stream>>>(tokB, w1B, b1, counts, tmeta, topos, Hbuf);
  gemm2_kernel<<<GRID_GEMM, 256, 0, stream>>>(Hbuf, w2B, b2, counts, tmeta, topos, out);
}

// Round 5
// 178.311 us; speedup vs baseline: 1.3138x; 1.0770x over previous
//
#include <hip/hip_runtime.h>
#include <hip/hip_bf16.h>
#include <stdint.h>

#define N_TOK 16384
#define HDIM  1024
#define NE    8

#define BM 128
#define BN 128
#define BK 64
#define NKT (HDIM / BK)            // 16
#define NT_N (HDIM / BN)           // 8
#define MAXTILES (N_TOK / BM + NE) // 136 worst-case row-tiles (136 % 8 == 0)
#define GRID_GEMM (MAXTILES * NT_N) // 1088

typedef __attribute__((ext_vector_type(8))) short          bf16x8;
typedef __attribute__((ext_vector_type(8))) unsigned short ushort8;
typedef __attribute__((ext_vector_type(4))) unsigned short ushort4v;
typedef __attribute__((ext_vector_type(4))) float          f32x4;

__device__ __forceinline__ unsigned short f2bf(float f) {
  union { float f; uint32_t u; } c; c.f = f;
  uint32_t u = c.u;
  uint32_t r = (u + 0x7fffu + ((u >> 16) & 1u)) >> 16;
  return (unsigned short)r;
}

__device__ __forceinline__ void gload_lds16(const void* g, void* l) {
  __builtin_amdgcn_global_load_lds((const __attribute__((address_space(1))) void*)g,
                                   (__attribute__((address_space(3))) void*)l, 16, 0, 0);
}

__device__ __forceinline__ void expert_range(const int* __restrict__ counts, int e,
                                             int& base, int& cnt) {
  int run = 0; base = 0; cnt = 0;
#pragma unroll
  for (int i = 0; i < NE; ++i) {
    int c = counts[i];
    if (i == e) { base = run; cnt = c; }
    run += c;
  }
}

// ---------------------------------------------------------------------------
// Gate: logits = tokens @ gate_w^T (f64 accum), top-1 argmax -> eid.
// Fuses token f32->bf16 conversion. One wave per token.
// ---------------------------------------------------------------------------
__global__ __launch_bounds__(256) void gate_kernel(
    const float* __restrict__ tokens, const float* __restrict__ gate_w,
    unsigned short* __restrict__ tokB, int* __restrict__ eid)
{
  int wid  = threadIdx.x >> 6;
  int lane = threadIdx.x & 63;
  int n    = blockIdx.x * 4 + wid;

  const float* trow = tokens + (size_t)n * HDIM;
  float4 x[4];
#pragma unroll
  for (int i = 0; i < 4; ++i)
    x[i] = *(const float4*)(trow + i * 256 + lane * 4);

  unsigned short* drow = tokB + (size_t)n * HDIM;
#pragma unroll
  for (int i = 0; i < 4; ++i) {
    ushort4v o;
    o[0] = f2bf(x[i].x); o[1] = f2bf(x[i].y);
    o[2] = f2bf(x[i].z); o[3] = f2bf(x[i].w);
    *(ushort4v*)(drow + i * 256 + lane * 4) = o;
  }

  double acc[NE];
#pragma unroll
  for (int e = 0; e < NE; ++e) {
    const float* grow = gate_w + e * HDIM;
    double a = 0.0;
#pragma unroll
    for (int i = 0; i < 4; ++i) {
      float4 g = *(const float4*)(grow + i * 256 + lane * 4);
      a += (double)x[i].x * g.x + (double)x[i].y * g.y
         + (double)x[i].z * g.z + (double)x[i].w * g.w;
    }
    acc[e] = a;
  }
#pragma unroll
  for (int off = 32; off; off >>= 1) {
#pragma unroll
    for (int e = 0; e < NE; ++e) acc[e] += __shfl_xor(acc[e], off);
  }
  if (lane == 0) {
    int best = 0; double bv = acc[0];
#pragma unroll
    for (int e = 1; e < NE; ++e) if (acc[e] > bv) { bv = acc[e]; best = e; }
    eid[n] = best;
  }
}

// ---------------------------------------------------------------------------
// Rank: LDS histogram per 256-token block; 8 global atomics per block.
// ---------------------------------------------------------------------------
__global__ __launch_bounds__(256) void rank_kernel(
    const int* __restrict__ eid, int* __restrict__ rank, int* __restrict__ counts)
{
  __shared__ int h[NE];
  __shared__ int bbase[NE];
  int t = threadIdx.x;
  int n = blockIdx.x * 256 + t;
  if (t < NE) h[t] = 0;
  __syncthreads();
  int e = eid[n];
  int r = atomicAdd(&h[e], 1);
  __syncthreads();
  if (t < NE) bbase[t] = atomicAdd(&counts[t], h[t]);
  __syncthreads();
  rank[n] = bbase[e] + r;
}

// perm: prefix over counts inline, scatter token index into expert-sorted order
__global__ __launch_bounds__(256) void perm_kernel(
    const int* __restrict__ counts, const int* __restrict__ eid,
    const int* __restrict__ rank, int* __restrict__ topos)
{
  __shared__ int off[NE];
  int t = threadIdx.x;
  if (t == 0) {
    int run = 0;
#pragma unroll
    for (int e = 0; e < NE; ++e) { off[e] = run; run += counts[e]; }
  }
  __syncthreads();
  int n = blockIdx.x * 256 + t;
  topos[off[eid[n]] + rank[n]] = n;
}

// tilemap: enumerate active (e, mt) row-tiles -> compact grid for the GEMMs.
// tmeta[0] = n_tiles; tmeta[1+i] = (mt<<3)|e
__global__ void tilemap_kernel(const int* __restrict__ counts, int* __restrict__ tmeta) {
  if (threadIdx.x == 0) {
    int idx = 0;
    for (int e = 0; e < NE; ++e) {
      int ntile = (counts[e] + BM - 1) / BM;
      for (int mt = 0; mt < ntile; ++mt) tmeta[1 + idx++] = (mt << 3) | e;
    }
    tmeta[0] = idx;
  }
}

// f32 -> bf16 for both weight tensors in one launch. 8 elems/thread.
__global__ __launch_bounds__(256) void cvt2_kernel(
    const float* __restrict__ w1, const float* __restrict__ w2,
    unsigned short* __restrict__ w1B, unsigned short* __restrict__ w2B)
{
  int b = blockIdx.x;
  const float* src; unsigned short* dst; size_t i;
  if (b < 4096) { src = w1; dst = w1B; i = (size_t)b * 256 + threadIdx.x; }
  else          { src = w2; dst = w2B; i = (size_t)(b - 4096) * 256 + threadIdx.x; }
  const float4* s = (const float4*)src + i * 2;
  float4 a = s[0], c = s[1];
  ushort8 o;
  o[0] = f2bf(a.x); o[1] = f2bf(a.y); o[2] = f2bf(a.z); o[3] = f2bf(a.w);
  o[4] = f2bf(c.x); o[5] = f2bf(c.y); o[6] = f2bf(c.z); o[7] = f2bf(c.w);
  ((ushort8*)dst)[i] = o;
}

// ---------------------------------------------------------------------------
// Grouped GEMM, m97 structure: 128x128 tile, BK=64, 4 waves (2x2), single
// LDS buffer, 2 syncthreads per K-tile, compiler-scheduled waits.
// LDS chunk-XOR swizzle (bank-conflict-free, verified 0 conflicts in r4).
// XCD-chunked swizzle: logical = (bid%8)*136 + bid/8, nt innermost ->
// each XCD owns 17 consecutive row-tiles (~one expert): B panel (2 MB)
// L2-resident, A-tile's 8 nt-blocks adjacent on the same XCD.
// ---------------------------------------------------------------------------
#define GEMM_PREAMBLE()                                                        \
  int bid = blockIdx.x;                                                        \
  int logical = (bid & 7) * (GRID_GEMM / 8) + (bid >> 3);                      \
  int tile = logical >> 3;                                                     \
  int nt   = logical & 7;                                                      \
  if (tile >= tmeta[0]) return;                                                \
  int ent = tmeta[1 + tile];                                                   \
  int e = ent & 7, mt = ent >> 3;                                              \
  int base, cnt;                                                               \
  expert_range(counts, e, base, cnt);                                          \
  __shared__ unsigned short Alds[BM * BK];                                     \
  __shared__ unsigned short Blds[BN * BK];                                     \
  int t    = threadIdx.x;                                                      \
  int kc   = t & 7;            /* 16B chunk within row */                      \
  int rowi = t >> 3;           /* 0..31 */                                     \
  int sch  = kc ^ (rowi & 7);  /* inverse-swizzled source chunk */             \
  int lane = t & 63, wid = t >> 6;                                             \
  int wr = wid >> 1, wc = wid & 1;                                             \
  f32x4 acc[4][4] = {};                                                        \
  int arow0 = wr * 64 + (lane & 15);                                           \
  int brow0 = wc * 64 + (lane & 15);                                           \
  int hi    = lane >> 4;       /* 0..3 */                                      \
  int xo    = lane & 7;        /* read-side XOR */

#define GEMM_STAGE(kt)                                                         \
  _Pragma("unroll")                                                            \
  for (int r = 0; r < 4; ++r) {                                                \
    gload_lds16(APTR(r, kt), Alds + t * 8 + 2048 * r);                         \
    gload_lds16(bsrc + (size_t)(kt) * BK + (size_t)(32 * r) * HDIM,            \
                Blds + t * 8 + 2048 * r);                                      \
  }

#define GEMM_COMPUTE()                                                         \
  _Pragma("unroll")                                                            \
  for (int ks = 0; ks < 2; ++ks) {                                             \
    int ch = ((ks * 4 + hi) ^ xo) * 8;                                         \
    bf16x8 af[4], bv[4];                                                       \
    _Pragma("unroll")                                                          \
    for (int m = 0; m < 4; ++m)                                                \
      af[m] = *(const bf16x8*)(Alds + (arow0 + m * 16) * BK + ch);             \
    _Pragma("unroll")                                                          \
    for (int n2 = 0; n2 < 4; ++n2)                                             \
      bv[n2] = *(const bf16x8*)(Blds + (brow0 + n2 * 16) * BK + ch);           \
    _Pragma("unroll")                                                          \
    for (int m = 0; m < 4; ++m)                                                \
      _Pragma("unroll")                                                        \
      for (int n2 = 0; n2 < 4; ++n2)                                           \
        acc[m][n2] = __builtin_amdgcn_mfma_f32_16x16x32_bf16(                  \
            af[m], bv[n2], acc[m][n2], 0, 0, 0);                               \
  }

#define GEMM_MAINLOOP()                                                        \
  for (int kt = 0; kt < NKT; ++kt) {                                           \
    __syncthreads();                                                           \
    GEMM_STAGE(kt);                                                            \
    __syncthreads();                                                           \
    GEMM_COMPUTE();                                                            \
  }

__global__ __launch_bounds__(256) void gemm1_kernel(
    const unsigned short* __restrict__ tokB,  // [N][H] token order
    const unsigned short* __restrict__ w1B,   // [E][H][H]
    const float* __restrict__ b1,             // [E][H]
    const int* __restrict__ counts,
    const int* __restrict__ tmeta,
    const int* __restrict__ topos,
    unsigned short* __restrict__ Hbuf)        // [N][H] compacted
{
  GEMM_PREAMBLE()
  int tokr[4];
#pragma unroll
  for (int r = 0; r < 4; ++r) {
    int pos = base + mt * BM + rowi + 32 * r;
    if (pos > N_TOK - 1) pos = N_TOK - 1;
    tokr[r] = topos[pos];
  }
  const unsigned short* bsrc =
      w1B + ((size_t)e << 20) + (size_t)(nt * BN + rowi) * HDIM + sch * 8;
#define APTR(r, kt) (tokB + (size_t)tokr[r] * HDIM + (kt) * BK + sch * 8)
  GEMM_MAINLOOP()
#undef APTR

  int crow0 = wr * 64 + (lane >> 4) * 4;
  int ccol0 = wc * 64 + (lane & 15);
  float bias[4];
#pragma unroll
  for (int n2 = 0; n2 < 4; ++n2)
    bias[n2] = b1[e * HDIM + nt * BN + ccol0 + n2 * 16];
#pragma unroll
  for (int m = 0; m < 4; ++m) {
#pragma unroll
    for (int j = 0; j < 4; ++j) {
      int row = crow0 + m * 16 + j;
      if (mt * BM + row < cnt) {
        size_t orow = (size_t)(base + mt * BM + row) * HDIM + nt * BN;
#pragma unroll
        for (int n2 = 0; n2 < 4; ++n2) {
          float v = acc[m][n2][j] + bias[n2];
          v = v > 0.f ? v : 0.f;
          Hbuf[orow + ccol0 + n2 * 16] = f2bf(v);
        }
      }
    }
  }
}

__global__ __launch_bounds__(256) void gemm2_kernel(
    const unsigned short* __restrict__ Hbuf,  // [N][H] compacted
    const unsigned short* __restrict__ w2B,   // [E][H][H]
    const float* __restrict__ b2,             // [E][H]
    const int* __restrict__ counts,
    const int* __restrict__ tmeta,
    const int* __restrict__ topos,
    float* __restrict__ out)                  // [N][H] token order
{
  GEMM_PREAMBLE()
  int arows[4];
#pragma unroll
  for (int r = 0; r < 4; ++r) {
    int pos = base + mt * BM + rowi + 32 * r;
    arows[r] = pos > N_TOK - 1 ? N_TOK - 1 : pos;
  }
  const unsigned short* bsrc =
      w2B + ((size_t)e << 20) + (size_t)(nt * BN + rowi) * HDIM + sch * 8;
#define APTR(r, kt) (Hbuf + (size_t)arows[r] * HDIM + (kt) * BK + sch * 8)
  GEMM_MAINLOOP()
#undef APTR

  int crow0 = wr * 64 + (lane >> 4) * 4;
  int ccol0 = wc * 64 + (lane & 15);
  float bias[4];
#pragma unroll
  for (int n2 = 0; n2 < 4; ++n2)
    bias[n2] = b2[e * HDIM + nt * BN + ccol0 + n2 * 16];
#pragma unroll
  for (int m = 0; m < 4; ++m) {
#pragma unroll
    for (int j = 0; j < 4; ++j) {
      int row = crow0 + m * 16 + j;
      if (mt * BM + row < cnt) {
        int tok = topos[base + mt * BM + row];
        size_t orow = (size_t)tok * HDIM + nt * BN;
#pragma unroll
        for (int n2 = 0; n2 < 4; ++n2)
          out[orow + ccol0 + n2 * 16] = acc[m][n2][j] + bias[n2];
      }
    }
  }
}

extern "C" void kernel_launch(void* const* d_in, const int* in_sizes, int n_in,
                              void* d_out, int out_size, void* d_ws, size_t ws_size,
                              hipStream_t stream) {
  (void)in_sizes; (void)n_in; (void)out_size; (void)ws_size;
  const float* tokens = (const float*)d_in[0];
  const float* gate_w = (const float*)d_in[1];
  const float* w1     = (const float*)d_in[2];
  const float* b1     = (const float*)d_in[3];
  const float* w2     = (const float*)d_in[4];
  const float* b2     = (const float*)d_in[5];
  float* out          = (float*)d_out;

  char* ws = (char*)d_ws;
  size_t o = 0;
  int* counts = (int*)(ws + o); o += 256;
  int* tmeta  = (int*)(ws + o); o += 1024;                 // n_tiles + entries
  int* eid    = (int*)(ws + o); o += (size_t)N_TOK * 4;
  int* rank   = (int*)(ws + o); o += (size_t)N_TOK * 4;
  int* topos  = (int*)(ws + o); o += (size_t)N_TOK * 4;
  unsigned short* tokB = (unsigned short*)(ws + o); o += (size_t)N_TOK * HDIM * 2;
  unsigned short* w1B  = (unsigned short*)(ws + o); o += (size_t)NE * HDIM * HDIM * 2;
  unsigned short* w2B  = (unsigned short*)(ws + o); o += (size_t)NE * HDIM * HDIM * 2;
  unsigned short* Hbuf = (unsigned short*)(ws + o); o += (size_t)N_TOK * HDIM * 2;

  hipMemsetAsync(counts, 0, 64, stream);
  gate_kernel<<<N_TOK / 4, 256, 0, stream>>>(tokens, gate_w, tokB, eid);
  cvt2_kernel<<<8192, 256, 0, stream>>>(w1, w2, w1B, w2B);
  rank_kernel<<<N_TOK / 256, 256, 0, stream>>>(eid, rank, counts);
  perm_kernel<<<N_TOK / 256, 256, 0, stream>>>(counts, eid, rank, topos);
  tilemap_kernel<<<1, 64, 0, stream>>>(counts, tmeta);
  gemm1_kernel<<<GRID_GEMM, 256, 0, stream>>>(tokB, w1B, b1, counts, tmeta, topos, Hbuf);
  gemm2_kernel<<<GRID_GEMM, 256, 0, stream>>>(Hbuf, w2B, b2, counts, tmeta, topos, out);
}